// Round 11
// baseline (130.902 us; speedup 1.0000x reference)
//
#include <hip/hip_runtime.h>
#include <hip/hip_bf16.h>
#include <stdint.h>

// ---------------------------------------------------------------------------
// SNN: x[512,784] -> FC(784->1024)+LIF -> FC(1024->1024)+LIF -> FC(1024->10)+LIF
// T=32, tau=2, vth=1, hard reset. Out = spike counts [512,10].
//
// Verified (R5-R10, absmax=0): layer-0 LIF exactly periodic (class=ctz+1);
// layer-1 current = divisor sum over class weight-sums; cur0 = exact 3-way
// bf16-split (6 cross-terms) MFMA GEMM, split-K x10; gemm0t_k's inline
// fp32->bf16 LDS staging is bit-identical to the prep path (R10).
//
// R10 lesson: fusing the tail into one 1024-thr kernel cost ~13us — S4
// (layer-1) needs 256-thr/8-blocks-per-CU shape for latency hiding; forcing
// one block shape loses more than the ~6us of gaps saved. Final structure:
// 4 kernels = gemm0t (inline split + W1T) -> compact0 -> layer1 -> layer2,
// each in its R9-proven shape.
// ---------------------------------------------------------------------------

typedef __bf16 bf16x8 __attribute__((ext_vector_type(8)));
typedef float  f32x4  __attribute__((ext_vector_type(4)));
typedef unsigned short u16x8 __attribute__((ext_vector_type(8)));

// bf16 component select: 0 -> h, 1 -> m = bf16(v-h), 2 -> l = bf16(v-h-m).
__device__ __forceinline__ unsigned short csel(float v, int sel) {
  __hip_bfloat16 h = __float2bfloat16(v);
  if (sel == 0) return __builtin_bit_cast(unsigned short, h);
  float r1 = v - __bfloat162float(h);
  __hip_bfloat16 m = __float2bfloat16(r1);
  if (sel == 1) return __builtin_bit_cast(unsigned short, m);
  float r2 = r1 - __bfloat162float(m);
  __hip_bfloat16 l = __float2bfloat16(r2);
  return __builtin_bit_cast(unsigned short, l);
}

// ---------------- kernel 1: split-K MFMA GEMM (inline split) + W1 transpose -
// Blocks [0,320): gemm (bx4 x by8 x bz10). Blocks [320,1344): W1 transpose.
// Segment s = kk/800 uniform per BK=32 iter; A comps {h,h,m,m,h,l}[s],
// B comps {h,m,h,m,l,h}[s]. LDS writer reproduces the gload16 swizzle
// (logical 16B group g of row r -> physical g ^ ((r>>1)&3)); reader
// (quad ^ swz) unchanged -> Cpart bit-identical to the R9 prep path.
__global__ __launch_bounds__(256, 2) void gemm0t_k(const float* __restrict__ x,
                                                   const float* __restrict__ W0,
                                                   const float* __restrict__ W1,
                                                   float* __restrict__ W1T,
                                                   float* __restrict__ Cpart) {
  __shared__ __align__(16) char smem[16512];
  const int bid = blockIdx.x, tid = threadIdx.x;

  if (bid >= 320) {                       // ---- W1 transpose tiles ----
    float (*t)[33] = (float(*)[33])smem;
    int tt = bid - 320;
    int c0 = (tt & 31) * 32, r0 = (tt >> 5) * 32;
    int lx = tid & 31, ly = tid >> 5;     // 32 x 8
#pragma unroll
    for (int i = 0; i < 32; i += 8)
      t[ly + i][lx] = W1[(size_t)(r0 + ly + i) * 1024 + (c0 + lx)];
    __syncthreads();
#pragma unroll
    for (int i = 0; i < 32; i += 8)
      W1T[(size_t)(c0 + ly + i) * 1024 + (r0 + lx)] = t[lx][ly + i];
    return;
  }

  // ---- gemm blocks ----
  const int bx = bid & 3, by = (bid >> 2) & 7, bz = bid >> 5;
  const int wave = tid >> 6, lane = tid & 63, quad = lane >> 4, l16 = lane & 15;
  const int wm = (wave >> 1) * 64, wn = (wave & 1) * 64;
  const int mbase = bx * 128, nbase = by * 128, kbase = bz * 480;
  const int swz = (l16 >> 1) & 3;

  // staging role: row r (0..127), col-half h (16 cols each)
  const int r = tid >> 1, h = tid & 1;
  const int sw = (r >> 1) & 3;
  const int swap = sw & 1;
  char* adst = smem + r * 64 + 32 * (h ^ (sw >> 1));
  char* bdst = smem + 8192 + r * 64 + 32 * (h ^ (sw >> 1));
  const float* xr = x + (size_t)(mbase + r) * 784;
  const float* wr = W0 + (size_t)(nbase + r) * 784;

  f32x4 acc[4][4] = {};

  for (int kk = kbase; kk < kbase + 480; kk += 32) {
    const int s = kk / 800;                        // uniform per iter
    const int k0 = kk - s * 800 + h * 16;          // this thread's col base
    const int selA = (s == 2 || s == 3) ? 1 : ((s == 5) ? 2 : 0);
    const int selB = (s == 1 || s == 3) ? 1 : ((s == 4) ? 2 : 0);
    {
      float v[16];
#pragma unroll
      for (int q = 0; q < 4; ++q) {
        int kq = k0 + q * 4;
        if (kq < 784) {
          f32x4 t4 = *(const f32x4*)(xr + kq);
          v[q*4+0] = t4[0]; v[q*4+1] = t4[1]; v[q*4+2] = t4[2]; v[q*4+3] = t4[3];
        } else {
          v[q*4+0] = 0.f; v[q*4+1] = 0.f; v[q*4+2] = 0.f; v[q*4+3] = 0.f;
        }
      }
      u16x8 c0v, c1v;
#pragma unroll
      for (int j = 0; j < 8; ++j) c0v[j] = csel(v[j], selA);
#pragma unroll
      for (int j = 0; j < 8; ++j) c1v[j] = csel(v[8 + j], selA);
      *(u16x8*)(adst + (swap ? 16 : 0)) = c0v;
      *(u16x8*)(adst + (swap ? 0 : 16)) = c1v;
    }
    {
      float v[16];
#pragma unroll
      for (int q = 0; q < 4; ++q) {
        int kq = k0 + q * 4;
        if (kq < 784) {
          f32x4 t4 = *(const f32x4*)(wr + kq);
          v[q*4+0] = t4[0]; v[q*4+1] = t4[1]; v[q*4+2] = t4[2]; v[q*4+3] = t4[3];
        } else {
          v[q*4+0] = 0.f; v[q*4+1] = 0.f; v[q*4+2] = 0.f; v[q*4+3] = 0.f;
        }
      }
      u16x8 c0v, c1v;
#pragma unroll
      for (int j = 0; j < 8; ++j) c0v[j] = csel(v[j], selB);
#pragma unroll
      for (int j = 0; j < 8; ++j) c1v[j] = csel(v[8 + j], selB);
      *(u16x8*)(bdst + (swap ? 16 : 0)) = c0v;
      *(u16x8*)(bdst + (swap ? 0 : 16)) = c1v;
    }
    __syncthreads();

    const __bf16* Ab = (const __bf16*)smem;
    const __bf16* Bb = Ab + 128 * 32;
    bf16x8 af[4], bfr[4];
#pragma unroll
    for (int i = 0; i < 4; ++i)
      af[i] = *(const bf16x8*)(Ab + (wm + i * 16 + l16) * 32 + ((quad ^ swz) * 8));
#pragma unroll
    for (int j = 0; j < 4; ++j)
      bfr[j] = *(const bf16x8*)(Bb + (wn + j * 16 + l16) * 32 + ((quad ^ swz) * 8));
#pragma unroll
    for (int i = 0; i < 4; ++i)
#pragma unroll
      for (int j = 0; j < 4; ++j)
        acc[i][j] = __builtin_amdgcn_mfma_f32_16x16x32_bf16(af[i], bfr[j], acc[i][j], 0, 0, 0);
    __syncthreads();
  }

  float* Cz = Cpart + (size_t)bz * 512 * 1024;
#pragma unroll
  for (int i = 0; i < 4; ++i)
#pragma unroll
    for (int j = 0; j < 4; ++j)
#pragma unroll
      for (int rr = 0; rr < 4; ++rr) {
        int m = mbase + wm + i * 16 + quad * 4 + rr;
        int n = nbase + wn + j * 16 + l16;
        Cz[(size_t)m * 1024 + n] = acc[i][j][rr];
      }
}

// ---------------- layer-0: split-K reduce + LIF + class compaction ----------
__global__ __launch_bounds__(1024) void compact0_k(const float* __restrict__ Cpart,
                                                   const float* __restrict__ b0,
                                                   unsigned short* __restrict__ lidx16,
                                                   int* __restrict__ segs) {
  __shared__ int whist[16][33];
  __shared__ int clstot[33];
  __shared__ int clsofs[34];
  __shared__ int wofs[16][33];
  int b = blockIdx.x, o = threadIdx.x;
  int wave = o >> 6, lane = o & 63;
  float cur = 0.f;
#pragma unroll
  for (int z = 0; z < 10; ++z)
    cur += Cpart[(size_t)z * 512 * 1024 + (size_t)b * 1024 + o];
  cur += b0[o];
  float v = 0.f;
  unsigned word = 0u;
#pragma unroll
  for (int t = 0; t < 32; ++t) {
    v = v + (cur - v) * 0.5f;            // exact: /2.0 == *0.5f
    if (v >= 1.0f) { word |= 1u << t; v = 0.f; }
  }
  int n = word ? (__builtin_ctz(word) + 1) : 0;
  unsigned long long mymask = 0ull;
#pragma unroll 1
  for (int c = 1; c <= 32; ++c) {
    unsigned long long m = __ballot(n == c);
    if (lane == 0) whist[wave][c] = __popcll(m);
    if (n == c) mymask = m;
  }
  __syncthreads();
  if (o < 32) {
    int c = o + 1, s = 0;
#pragma unroll
    for (int w = 0; w < 16; ++w) s += whist[w][c];
    clstot[c] = s;
  }
  __syncthreads();
  if (o == 0) {
    int run = 0;
#pragma unroll
    for (int c = 1; c <= 32; ++c) { clsofs[c] = run; run += clstot[c]; }
    clsofs[33] = run;
  }
  __syncthreads();
  if (o < 32) {
    int c = o + 1, s = clsofs[c];
#pragma unroll
    for (int w = 0; w < 16; ++w) { wofs[w][c] = s; s += whist[w][c]; }
  }
  __syncthreads();
  if (n) {
    int pos = wofs[wave][n] + __popcll(mymask & ((1ull << lane) - 1ull));
    lidx16[(size_t)b * 1024 + pos] = (unsigned short)o;
  }
  if (o < 33) segs[b * 33 + o] = clsofs[o + 1];
}

// ---------------- layer-1: class-sum + divisor-table LIF + compaction -------
__global__ __launch_bounds__(256) void layer1_k(const unsigned short* __restrict__ lidx16,
                                                const int* __restrict__ segs,
                                                const float* __restrict__ W1T,
                                                const float* __restrict__ b1,
                                                unsigned* __restrict__ l2idx,
                                                unsigned* __restrict__ l2wrd,
                                                int* __restrict__ n2t) {
  __shared__ unsigned short sidx[1024];
  __shared__ int sseg[33];
  __shared__ int wtot[4], wbase[4];
  const int tile = blockIdx.x, b = blockIdx.y;
  const int tid = threadIdx.x;
  const int o = tile * 256 + tid;
  if (tid < 33) sseg[tid] = segs[b * 33 + tid];
  __syncthreads();
  const int total = __builtin_amdgcn_readfirstlane(sseg[32]);
  for (int i = tid; i < total; i += 256)
    sidx[i] = lidx16[(size_t)b * 1024 + i];
  __syncthreads();
  float S[32];
#pragma unroll
  for (int c = 0; c < 32; ++c) {
    int j0 = __builtin_amdgcn_readfirstlane((c == 0) ? 0 : sseg[c - 1]);
    int j1 = __builtin_amdgcn_readfirstlane(sseg[c]);
    float s = 0.f;
    for (int j = j0; j < j1; ++j)
      s += W1T[(size_t)sidx[j] * 1024 + o];
    S[c] = s;
  }
  const float bias = b1[o];
  float v = 0.f;
  unsigned word = 0u;
#pragma unroll
  for (int t = 0; t < 32; ++t) {
    float cur = 0.f;
#pragma unroll
    for (int c = 1; c <= 32; ++c)
      if ((t + 1) % c == 0) cur += S[c - 1];   // compile-time divisor table
    float xc = cur + bias;
    v = v + (xc - v) * 0.5f;
    if (v >= 1.0f) { word |= 1u << t; v = 0.f; }
  }
  bool act = (word != 0u);
  unsigned long long m = __ballot(act);
  int wave = tid >> 6, lane = tid & 63;
  if (lane == 0) wtot[wave] = __popcll(m);
  __syncthreads();
  if (tid == 0) {
    int s = 0;
#pragma unroll
    for (int i = 0; i < 4; ++i) { wbase[i] = s; s += wtot[i]; }
    n2t[b * 4 + tile] = s;
  }
  __syncthreads();
  if (act) {
    int pos = wbase[wave] + __popcll(m & ((1ull << lane) - 1ull));
    l2idx[(size_t)b * 1024 + tile * 256 + pos] = (unsigned)o;
    l2wrd[(size_t)b * 1024 + tile * 256 + pos] = word;
  }
}

// ---------------- layer-2: sparse FC + LIF + count --------------------------
__global__ __launch_bounds__(320) void layer2_k(const unsigned* __restrict__ l2idx,
                                                const unsigned* __restrict__ l2wrd,
                                                const int* __restrict__ n2t,
                                                const float* __restrict__ W2,
                                                const float* __restrict__ b2,
                                                float* __restrict__ out) {
  __shared__ float sW2[10 * 1025];
  __shared__ unsigned sidx[1024], swrd[1024];
  __shared__ float scur[320];
  int b = blockIdx.x, tid = threadIdx.x;
  int cnt[4], ofs[4], mtot = 0;
#pragma unroll
  for (int s = 0; s < 4; ++s) {
    cnt[s] = n2t[b * 4 + s];
    ofs[s] = mtot;
    mtot += cnt[s];
  }
  for (int i = tid; i < 10240; i += 320)
    sW2[(i >> 10) * 1025 + (i & 1023)] = W2[i];
#pragma unroll
  for (int s = 0; s < 4; ++s)
    for (int i = tid; i < cnt[s]; i += 320) {
      sidx[ofs[s] + i] = l2idx[(size_t)b * 1024 + s * 256 + i];
      swrd[ofs[s] + i] = l2wrd[(size_t)b * 1024 + s * 256 + i];
    }
  __syncthreads();
  int t = tid / 10, c = tid - t * 10;
  float acc = 0.f;
  for (int j = 0; j < mtot; ++j) {
    unsigned wd = swrd[j];
    float wv = sW2[c * 1025 + sidx[j]];
    acc += ((wd >> t) & 1u) ? wv : 0.f;
  }
  scur[t * 10 + c] = acc;
  __syncthreads();
  if (tid < 10) {
    float v = 0.f, cnt2 = 0.f, bias = b2[tid];
#pragma unroll
    for (int tt = 0; tt < 32; ++tt) {
      float xc = scur[tt * 10 + tid] + bias;
      v = v + (xc - v) * 0.5f;
      if (v >= 1.0f) { cnt2 += 1.f; v = 0.f; }
    }
    out[(size_t)b * 10 + tid] = cnt2;
  }
}

// ---------------------------------------------------------------------------
extern "C" void kernel_launch(void* const* d_in, const int* in_sizes, int n_in,
                              void* d_out, int out_size, void* d_ws, size_t ws_size,
                              hipStream_t stream) {
  const float* x  = (const float*)d_in[0];   // [512,784]
  const float* W0 = (const float*)d_in[1];   // [1024,784]
  const float* b0 = (const float*)d_in[2];   // [1024]
  const float* W1 = (const float*)d_in[3];   // [1024,1024]
  const float* b1 = (const float*)d_in[4];   // [1024]
  const float* W2 = (const float*)d_in[5];   // [10,1024]
  const float* b2 = (const float*)d_in[6];   // [10]
  float* out = (float*)d_out;                // [512,10]

  char* ws = (char*)d_ws;
  size_t off = 0;
  auto alloc = [&](size_t bytes) -> char* {
    char* p = ws + off;
    off += (bytes + 255) & ~(size_t)255;
    return p;
  };
  float*          Cpart  = (float*)alloc((size_t)10 * 512 * 1024 * 4);   // 21 MB
  float*          W1T    = (float*)alloc((size_t)1024 * 1024 * 4);       // 4.2 MB
  unsigned short* lidx16 = (unsigned short*)alloc((size_t)512 * 1024 * 2);
  int*            segs   = (int*)alloc((size_t)512 * 33 * 4);
  unsigned*       l2idx  = (unsigned*)alloc((size_t)512 * 1024 * 4);
  unsigned*       l2wrd  = (unsigned*)alloc((size_t)512 * 1024 * 4);
  int*            n2t    = (int*)alloc((size_t)512 * 4 * 4);
  (void)ws_size;

  gemm0t_k<<<1344, 256, 0, stream>>>(x, W0, W1, W1T, Cpart);
  compact0_k<<<512, 1024, 0, stream>>>(Cpart, b0, lidx16, segs);
  layer1_k<<<dim3(4, 512), 256, 0, stream>>>(lidx16, segs, W1T, b1, l2idx, l2wrd, n2t);
  layer2_k<<<512, 320, 0, stream>>>(l2idx, l2wrd, n2t, W2, b2, out);
}

// Round 12
// 114.226 us; speedup vs baseline: 1.1460x; 1.1460x over previous
//
#include <hip/hip_runtime.h>
#include <hip/hip_bf16.h>
#include <stdint.h>

// ---------------------------------------------------------------------------
// SNN: x[512,784] -> FC(784->1024)+LIF -> FC(1024->1024)+LIF -> FC(1024->10)+LIF
// T=32, tau=2, vth=1, hard reset. Out = spike counts [512,10].
//
// Verified (R5-R11, absmax=0): layer-0 LIF exactly periodic (class=ctz+1);
// layer-1 current = divisor sum over class weight-sums; cur0 = exact 3-way
// bf16-split (6 cross-terms) MFMA GEMM, split-K x10 for occupancy.
//
// R11 lesson (corrects R10's wrong diagnosis): the inline-split gemm0t_k was
// the 40us regression (8 scattered fp32 VMEM loads/thread/iter + vmcnt(0) +
// convert chain at 4 waves/CU — vs global_load_lds's 2 staging instrs);
// R10's fused tail_k was actually ~6us (vs ~19us+2gaps split). Final:
//   prep_k  (R9): bf16 splits + W1 transpose, one grid-partitioned kernel
//   gemm0_k (R9): split-K x10 MFMA with global_load_lds staging
//   tail_k  (R10): compact0 + layer1 + layer2 fused per batch
// 3 kernels, 2 gaps. Every component bit-proven in its source round.
// ---------------------------------------------------------------------------

typedef __bf16 bf16x8 __attribute__((ext_vector_type(8)));
typedef float  f32x4  __attribute__((ext_vector_type(4)));

__device__ __forceinline__ void gload16(const void* g, void* l) {
  __builtin_amdgcn_global_load_lds((const __attribute__((address_space(1))) void*)g,
                                   (__attribute__((address_space(3))) void*)l,
                                   16, 0, 0);
}

__device__ __forceinline__ void bsplit3(float v, __hip_bfloat16& h,
                                        __hip_bfloat16& m, __hip_bfloat16& l) {
  h = __float2bfloat16(v);
  float r1 = v - __bfloat162float(h);
  m = __float2bfloat16(r1);
  float r2 = r1 - __bfloat162float(m);
  l = __float2bfloat16(r2);
}

// ---------------- prep: bf16 splits of x & W0 + W1 transpose (one kernel) ---
// Block-uniform partition: [0,1600) splitx, [1600,4800) splitw,
// [4800,5824) W1-transpose 32x32 tiles. (R9 verbatim)
__global__ __launch_bounds__(256) void prep_k(const float* __restrict__ x,
                                              const float* __restrict__ W0,
                                              const float* __restrict__ W1,
                                              __hip_bfloat16* __restrict__ Ax,
                                              __hip_bfloat16* __restrict__ Bw,
                                              float* __restrict__ W1T) {
  const int bid = blockIdx.x, tid = threadIdx.x;
  if (bid < 1600) {                       // splitx: 512*800 elements
    int i = bid * 256 + tid;
    int m = i / 800, k = i - m * 800;
    float v = (k < 784) ? x[(size_t)m * 784 + k] : 0.f;
    __hip_bfloat16 h, mm, l;
    bsplit3(v, h, mm, l);
    size_t base = (size_t)m * 4800;
    Ax[base + k] = h;         Ax[base + 800 + k] = h;
    Ax[base + 1600 + k] = mm; Ax[base + 2400 + k] = mm;
    Ax[base + 3200 + k] = h;  Ax[base + 4000 + k] = l;
  } else if (bid < 4800) {                // splitw: 1024*800 elements
    int i = (bid - 1600) * 256 + tid;
    int n = i / 800, k = i - n * 800;
    float v = (k < 784) ? W0[(size_t)n * 784 + k] : 0.f;
    __hip_bfloat16 h, mm, l;
    bsplit3(v, h, mm, l);
    size_t base = (size_t)n * 4800;
    Bw[base + k] = h;         Bw[base + 800 + k] = mm;
    Bw[base + 1600 + k] = h;  Bw[base + 2400 + k] = mm;
    Bw[base + 3200 + k] = l;  Bw[base + 4000 + k] = h;
  } else {                                // W1 transpose: 1024 32x32 tiles
    __shared__ float t[32][33];
    int tt = bid - 4800;
    int c0 = (tt & 31) * 32, r0 = (tt >> 5) * 32;
    int lx = tid & 31, ly = tid >> 5;     // 32 x 8
#pragma unroll
    for (int i = 0; i < 32; i += 8)
      t[ly + i][lx] = W1[(size_t)(r0 + ly + i) * 1024 + (c0 + lx)];
    __syncthreads();
#pragma unroll
    for (int i = 0; i < 32; i += 8)
      W1T[(size_t)(c0 + ly + i) * 1024 + (r0 + lx)] = t[lx][ly + i];
  }
}

// ---------------- gemm0 split-K: partial[z] = Ax x Bw^T over K-chunk z ------
// 128x128 tile, BK=32, global_load_lds(16B), XOR quad swizzle. Grid (4,8,10)
// = 320 blocks (~1.25/CU). (R9 verbatim)
__global__ __launch_bounds__(256, 2) void gemm0_k(const __hip_bfloat16* __restrict__ A,
                                                  const __hip_bfloat16* __restrict__ B,
                                                  float* __restrict__ Cpart) {
  __shared__ __align__(16) __hip_bfloat16 As[128 * 32];
  __shared__ __align__(16) __hip_bfloat16 Bs[128 * 32];
  const int tid = threadIdx.x;
  const int wave = tid >> 6, lane = tid & 63, quad = lane >> 4, l16 = lane & 15;
  const int wm = (wave >> 1) * 64, wn = (wave & 1) * 64;
  const int mbase = blockIdx.x * 128, nbase = blockIdx.y * 128;
  const int kbase = blockIdx.z * 480;
  const int srow = lane >> 2;
  const int gq = (lane & 3) ^ ((lane >> 3) & 3);
  const int swz = (l16 >> 1) & 3;
  f32x4 acc[4][4] = {};
  for (int kk = kbase; kk < kbase + 480; kk += 32) {
#pragma unroll
    for (int r = 0; r < 2; ++r) {
      int grp = wave * 2 + r;
      gload16(A + (size_t)(mbase + grp * 16 + srow) * 4800 + kk + gq * 8,
              (char*)As + grp * 1024);
      gload16(B + (size_t)(nbase + grp * 16 + srow) * 4800 + kk + gq * 8,
              (char*)Bs + grp * 1024);
    }
    __syncthreads();
    const __bf16* Ab = (const __bf16*)As;
    const __bf16* Bb = (const __bf16*)Bs;
    bf16x8 af[4], bfr[4];
#pragma unroll
    for (int i = 0; i < 4; ++i)
      af[i] = *(const bf16x8*)(Ab + (wm + i * 16 + l16) * 32 + ((quad ^ swz) * 8));
#pragma unroll
    for (int j = 0; j < 4; ++j)
      bfr[j] = *(const bf16x8*)(Bb + (wn + j * 16 + l16) * 32 + ((quad ^ swz) * 8));
#pragma unroll
    for (int i = 0; i < 4; ++i)
#pragma unroll
      for (int j = 0; j < 4; ++j)
        acc[i][j] = __builtin_amdgcn_mfma_f32_16x16x32_bf16(af[i], bfr[j], acc[i][j], 0, 0, 0);
    __syncthreads();
  }
  float* Cz = Cpart + (size_t)blockIdx.z * 512 * 1024;
#pragma unroll
  for (int i = 0; i < 4; ++i)
#pragma unroll
    for (int j = 0; j < 4; ++j)
#pragma unroll
      for (int r = 0; r < 4; ++r) {
        int m = mbase + wm + i * 16 + quad * 4 + r;
        int n = nbase + wn + j * 16 + l16;
        Cz[(size_t)m * 1024 + n] = acc[i][j][r];
      }
}

// ---------------- fused tail (compact0 + layer1 + layer2), R10 verbatim -----
// One block per batch, 1024 threads. All inter-stage data in LDS. ~6us (R10).
struct TailSM {
  unsigned short sidx[1024];
  int sseg[33];
  int mtot;
  unsigned l2i[1024];
  unsigned l2w[1024];
  union {
    struct { int whist[16][33]; int clstot[33]; int clsofs[34]; int wofs[16][33]; } s3;
    struct { int wtot[16]; int wbase[16]; } s4;
    struct { float sW2[10 * 1025]; float scur[320]; } s5;
  } u;
};

__global__ __launch_bounds__(1024) void tail_k(const float* __restrict__ Cpart,
                                               const float* __restrict__ b0,
                                               const float* __restrict__ W1T,
                                               const float* __restrict__ b1,
                                               const float* __restrict__ W2,
                                               const float* __restrict__ b2,
                                               float* __restrict__ out) {
  __shared__ TailSM sm;
  const int b = blockIdx.x, o = threadIdx.x;
  const int wave = o >> 6, lane = o & 63;

  // ---- S3: split-K reduce + LIF + class compaction ----
  {
    float cur = 0.f;
#pragma unroll
    for (int z = 0; z < 10; ++z)
      cur += Cpart[(size_t)z * 512 * 1024 + (size_t)b * 1024 + o];
    cur += b0[o];
    float v = 0.f;
    unsigned word = 0u;
#pragma unroll
    for (int t = 0; t < 32; ++t) {
      v = v + (cur - v) * 0.5f;            // exact: /2.0 == *0.5f
      if (v >= 1.0f) { word |= 1u << t; v = 0.f; }
    }
    int n = word ? (__builtin_ctz(word) + 1) : 0;
    unsigned long long mymask = 0ull;
#pragma unroll 1
    for (int c = 1; c <= 32; ++c) {
      unsigned long long m = __ballot(n == c);
      if (lane == 0) sm.u.s3.whist[wave][c] = __popcll(m);
      if (n == c) mymask = m;
    }
    __syncthreads();
    if (o < 32) {
      int c = o + 1, s = 0;
#pragma unroll
      for (int w = 0; w < 16; ++w) s += sm.u.s3.whist[w][c];
      sm.u.s3.clstot[c] = s;
    }
    __syncthreads();
    if (o == 0) {
      int run = 0;
#pragma unroll
      for (int c = 1; c <= 32; ++c) { sm.u.s3.clsofs[c] = run; run += sm.u.s3.clstot[c]; }
      sm.u.s3.clsofs[33] = run;
    }
    __syncthreads();
    if (o < 32) {
      int c = o + 1, s = sm.u.s3.clsofs[c];
#pragma unroll
      for (int w = 0; w < 16; ++w) { sm.u.s3.wofs[w][c] = s; s += sm.u.s3.whist[w][c]; }
    }
    __syncthreads();
    if (n) {
      int pos = sm.u.s3.wofs[wave][n] + __popcll(mymask & ((1ull << lane) - 1ull));
      sm.sidx[pos] = (unsigned short)o;
    }
    if (o < 33) sm.sseg[o] = sm.u.s3.clsofs[o + 1];
  }
  __syncthreads();

  // ---- S4: layer-1 class-sums + divisor LIF + compaction ----
  {
    float S[32];
#pragma unroll
    for (int c = 0; c < 32; ++c) {
      int j0 = __builtin_amdgcn_readfirstlane((c == 0) ? 0 : sm.sseg[c - 1]);
      int j1 = __builtin_amdgcn_readfirstlane(sm.sseg[c]);
      float s = 0.f;
      for (int j = j0; j < j1; ++j)
        s += W1T[(size_t)sm.sidx[j] * 1024 + o];
      S[c] = s;
    }
    const float bias = b1[o];
    float v = 0.f;
    unsigned word = 0u;
#pragma unroll
    for (int t = 0; t < 32; ++t) {
      float cur = 0.f;
#pragma unroll
      for (int c = 1; c <= 32; ++c)
        if ((t + 1) % c == 0) cur += S[c - 1];   // compile-time divisor table
      float xc = cur + bias;
      v = v + (xc - v) * 0.5f;
      if (v >= 1.0f) { word |= 1u << t; v = 0.f; }
    }
    bool act = (word != 0u);
    unsigned long long m = __ballot(act);
    if (lane == 0) sm.u.s4.wtot[wave] = __popcll(m);
    __syncthreads();
    if (o == 0) {
      int s = 0;
#pragma unroll
      for (int i = 0; i < 16; ++i) { sm.u.s4.wbase[i] = s; s += sm.u.s4.wtot[i]; }
      sm.mtot = s;
    }
    __syncthreads();
    if (act) {
      int pos = sm.u.s4.wbase[wave] + __popcll(m & ((1ull << lane) - 1ull));
      sm.l2i[pos] = (unsigned)o;
      sm.l2w[pos] = word;
    }
  }
  __syncthreads();

  // ---- S5: layer-2 sparse FC + LIF + count ----
  {
    for (int i = o; i < 10240; i += 1024)
      sm.u.s5.sW2[(i >> 10) * 1025 + (i & 1023)] = W2[i];
    __syncthreads();
    const int mtot = sm.mtot;
    if (o < 320) {
      int t = o / 10, c = o - t * 10;
      float acc = 0.f;
      for (int j = 0; j < mtot; ++j) {
        unsigned wd = sm.l2w[j];
        float wv = sm.u.s5.sW2[c * 1025 + sm.l2i[j]];
        acc += ((wd >> t) & 1u) ? wv : 0.f;
      }
      sm.u.s5.scur[o] = acc;
    }
    __syncthreads();
    if (o < 10) {
      float v = 0.f, cnt2 = 0.f, bias = b2[o];
#pragma unroll
      for (int tt = 0; tt < 32; ++tt) {
        float xc = sm.u.s5.scur[tt * 10 + o] + bias;
        v = v + (xc - v) * 0.5f;
        if (v >= 1.0f) { cnt2 += 1.f; v = 0.f; }
      }
      out[(size_t)b * 10 + o] = cnt2;
    }
  }
}

// ---------------------------------------------------------------------------
extern "C" void kernel_launch(void* const* d_in, const int* in_sizes, int n_in,
                              void* d_out, int out_size, void* d_ws, size_t ws_size,
                              hipStream_t stream) {
  const float* x  = (const float*)d_in[0];   // [512,784]
  const float* W0 = (const float*)d_in[1];   // [1024,784]
  const float* b0 = (const float*)d_in[2];   // [1024]
  const float* W1 = (const float*)d_in[3];   // [1024,1024]
  const float* b1 = (const float*)d_in[4];   // [1024]
  const float* W2 = (const float*)d_in[5];   // [10,1024]
  const float* b2 = (const float*)d_in[6];   // [10]
  float* out = (float*)d_out;                // [512,10]

  char* ws = (char*)d_ws;
  size_t off = 0;
  auto alloc = [&](size_t bytes) -> char* {
    char* p = ws + off;
    off += (bytes + 255) & ~(size_t)255;
    return p;
  };
  __hip_bfloat16* Ax    = (__hip_bfloat16*)alloc((size_t)512 * 4800 * 2);   // 4.7 MB
  __hip_bfloat16* Bw    = (__hip_bfloat16*)alloc((size_t)1024 * 4800 * 2);  // 9.4 MB
  float*          Cpart = (float*)alloc((size_t)10 * 512 * 1024 * 4);       // 21 MB
  float*          W1T   = (float*)alloc((size_t)1024 * 1024 * 4);           // 4.2 MB
  (void)ws_size;

  prep_k<<<5824, 256, 0, stream>>>(x, W0, W1, Ax, Bw, W1T);
  gemm0_k<<<dim3(4, 8, 10), 256, 0, stream>>>(Ax, Bw, Cpart);
  tail_k<<<512, 1024, 0, stream>>>(Cpart, b0, W1T, b1, W2, b2, out);
}

// Round 13
// 111.329 us; speedup vs baseline: 1.1758x; 1.0260x over previous
//
#include <hip/hip_runtime.h>
#include <hip/hip_bf16.h>
#include <stdint.h>

// ---------------------------------------------------------------------------
// SNN: x[512,784] -> FC(784->1024)+LIF -> FC(1024->1024)+LIF -> FC(1024->10)+LIF
// T=32, tau=2, vth=1, hard reset. Out = spike counts [512,10].
//
// Verified (R5-R12, absmax=0): layer-0 LIF exactly periodic (class=ctz+1);
// layer-1 current = divisor sum over class weight-sums; cur0 = exact 3-way
// bf16-split (6 cross-terms hh,hm,mh,mm,hl,lh) MFMA GEMM, split-K x10.
//
// Structure (R12 best = 114.2us, ~78us of which is harness fill/restore):
//   prep_k:   bf16 splits of x & W0 only (4800 blocks, memory-bound)
//   gemm0t_k: split-K MFMA (blocks 0..319, global_load_lds staging) + W1
//             transpose (blocks 320..1343) — transpose fills the ~200 CUs
//             idle during the 1.25-block/CU gemm phase (R13 change)
//   tail_k:   compact0 + layer1 + layer2 fused per batch (R10, ~6us)
// 3 kernels, 2 gaps. R11 proved the transpose-in-gemm-grid partition is
// safe; it was the inline SPLIT staging that regressed, which stays out.
// ---------------------------------------------------------------------------

typedef __bf16 bf16x8 __attribute__((ext_vector_type(8)));
typedef float  f32x4  __attribute__((ext_vector_type(4)));

__device__ __forceinline__ void gload16(const void* g, void* l) {
  __builtin_amdgcn_global_load_lds((const __attribute__((address_space(1))) void*)g,
                                   (__attribute__((address_space(3))) void*)l,
                                   16, 0, 0);
}

__device__ __forceinline__ void bsplit3(float v, __hip_bfloat16& h,
                                        __hip_bfloat16& m, __hip_bfloat16& l) {
  h = __float2bfloat16(v);
  float r1 = v - __bfloat162float(h);
  m = __float2bfloat16(r1);
  float r2 = r1 - __bfloat162float(m);
  l = __float2bfloat16(r2);
}

// ---------------- prep: bf16 splits of x & W0 (R9 split code verbatim) ------
// [0,1600) splitx, [1600,4800) splitw.
__global__ __launch_bounds__(256) void prep_k(const float* __restrict__ x,
                                              const float* __restrict__ W0,
                                              __hip_bfloat16* __restrict__ Ax,
                                              __hip_bfloat16* __restrict__ Bw) {
  const int bid = blockIdx.x, tid = threadIdx.x;
  if (bid < 1600) {                       // splitx: 512*800 elements
    int i = bid * 256 + tid;
    int m = i / 800, k = i - m * 800;
    float v = (k < 784) ? x[(size_t)m * 784 + k] : 0.f;
    __hip_bfloat16 h, mm, l;
    bsplit3(v, h, mm, l);
    size_t base = (size_t)m * 4800;
    Ax[base + k] = h;         Ax[base + 800 + k] = h;
    Ax[base + 1600 + k] = mm; Ax[base + 2400 + k] = mm;
    Ax[base + 3200 + k] = h;  Ax[base + 4000 + k] = l;
  } else {                                // splitw: 1024*800 elements
    int i = (bid - 1600) * 256 + tid;
    int n = i / 800, k = i - n * 800;
    float v = (k < 784) ? W0[(size_t)n * 784 + k] : 0.f;
    __hip_bfloat16 h, mm, l;
    bsplit3(v, h, mm, l);
    size_t base = (size_t)n * 4800;
    Bw[base + k] = h;         Bw[base + 800 + k] = mm;
    Bw[base + 1600 + k] = h;  Bw[base + 2400 + k] = mm;
    Bw[base + 3200 + k] = l;  Bw[base + 4000 + k] = h;
  }
}

// ---------------- gemm0 split-K (global_load_lds) + W1 transpose ------------
// Blocks [0,320): gemm, decode bx(4) x by(8) x bz(10) — R9 gemm0_k verbatim.
// Blocks [320,1344): W1 32x32 transpose tiles (overlap gemm's idle CUs).
__global__ __launch_bounds__(256, 2) void gemm0t_k(const __hip_bfloat16* __restrict__ A,
                                                   const __hip_bfloat16* __restrict__ B,
                                                   const float* __restrict__ W1,
                                                   float* __restrict__ W1T,
                                                   float* __restrict__ Cpart) {
  __shared__ __align__(16) char smem[16384];
  const int bid = blockIdx.x, tid = threadIdx.x;

  if (bid >= 320) {                       // ---- W1 transpose tiles ----
    float (*t)[33] = (float(*)[33])smem;  // 4.2 KB of the 16 KB
    int tt = bid - 320;
    int c0 = (tt & 31) * 32, r0 = (tt >> 5) * 32;
    int lx = tid & 31, ly = tid >> 5;     // 32 x 8
#pragma unroll
    for (int i = 0; i < 32; i += 8)
      t[ly + i][lx] = W1[(size_t)(r0 + ly + i) * 1024 + (c0 + lx)];
    __syncthreads();
#pragma unroll
    for (int i = 0; i < 32; i += 8)
      W1T[(size_t)(c0 + ly + i) * 1024 + (r0 + lx)] = t[lx][ly + i];
    return;
  }

  // ---- gemm blocks (R9 gemm0_k verbatim) ----
  __hip_bfloat16* As = (__hip_bfloat16*)smem;
  __hip_bfloat16* Bs = As + 128 * 32;
  const int bx = bid & 3, by = (bid >> 2) & 7, bz = bid >> 5;
  const int wave = tid >> 6, lane = tid & 63, quad = lane >> 4, l16 = lane & 15;
  const int wm = (wave >> 1) * 64, wn = (wave & 1) * 64;
  const int mbase = bx * 128, nbase = by * 128, kbase = bz * 480;
  const int srow = lane >> 2;
  const int gq = (lane & 3) ^ ((lane >> 3) & 3);
  const int swz = (l16 >> 1) & 3;
  f32x4 acc[4][4] = {};
  for (int kk = kbase; kk < kbase + 480; kk += 32) {
#pragma unroll
    for (int r = 0; r < 2; ++r) {
      int grp = wave * 2 + r;
      gload16(A + (size_t)(mbase + grp * 16 + srow) * 4800 + kk + gq * 8,
              (char*)As + grp * 1024);
      gload16(B + (size_t)(nbase + grp * 16 + srow) * 4800 + kk + gq * 8,
              (char*)Bs + grp * 1024);
    }
    __syncthreads();
    const __bf16* Ab = (const __bf16*)As;
    const __bf16* Bb = (const __bf16*)Bs;
    bf16x8 af[4], bfr[4];
#pragma unroll
    for (int i = 0; i < 4; ++i)
      af[i] = *(const bf16x8*)(Ab + (wm + i * 16 + l16) * 32 + ((quad ^ swz) * 8));
#pragma unroll
    for (int j = 0; j < 4; ++j)
      bfr[j] = *(const bf16x8*)(Bb + (wn + j * 16 + l16) * 32 + ((quad ^ swz) * 8));
#pragma unroll
    for (int i = 0; i < 4; ++i)
#pragma unroll
      for (int j = 0; j < 4; ++j)
        acc[i][j] = __builtin_amdgcn_mfma_f32_16x16x32_bf16(af[i], bfr[j], acc[i][j], 0, 0, 0);
    __syncthreads();
  }
  float* Cz = Cpart + (size_t)bz * 512 * 1024;
#pragma unroll
  for (int i = 0; i < 4; ++i)
#pragma unroll
    for (int j = 0; j < 4; ++j)
#pragma unroll
      for (int r = 0; r < 4; ++r) {
        int m = mbase + wm + i * 16 + quad * 4 + r;
        int n = nbase + wn + j * 16 + l16;
        Cz[(size_t)m * 1024 + n] = acc[i][j][r];
      }
}

// ---------------- fused tail (compact0 + layer1 + layer2), R10 verbatim -----
struct TailSM {
  unsigned short sidx[1024];
  int sseg[33];
  int mtot;
  unsigned l2i[1024];
  unsigned l2w[1024];
  union {
    struct { int whist[16][33]; int clstot[33]; int clsofs[34]; int wofs[16][33]; } s3;
    struct { int wtot[16]; int wbase[16]; } s4;
    struct { float sW2[10 * 1025]; float scur[320]; } s5;
  } u;
};

__global__ __launch_bounds__(1024) void tail_k(const float* __restrict__ Cpart,
                                               const float* __restrict__ b0,
                                               const float* __restrict__ W1T,
                                               const float* __restrict__ b1,
                                               const float* __restrict__ W2,
                                               const float* __restrict__ b2,
                                               float* __restrict__ out) {
  __shared__ TailSM sm;
  const int b = blockIdx.x, o = threadIdx.x;
  const int wave = o >> 6, lane = o & 63;

  // ---- S3: split-K reduce + LIF + class compaction ----
  {
    float cur = 0.f;
#pragma unroll
    for (int z = 0; z < 10; ++z)
      cur += Cpart[(size_t)z * 512 * 1024 + (size_t)b * 1024 + o];
    cur += b0[o];
    float v = 0.f;
    unsigned word = 0u;
#pragma unroll
    for (int t = 0; t < 32; ++t) {
      v = v + (cur - v) * 0.5f;            // exact: /2.0 == *0.5f
      if (v >= 1.0f) { word |= 1u << t; v = 0.f; }
    }
    int n = word ? (__builtin_ctz(word) + 1) : 0;
    unsigned long long mymask = 0ull;
#pragma unroll 1
    for (int c = 1; c <= 32; ++c) {
      unsigned long long m = __ballot(n == c);
      if (lane == 0) sm.u.s3.whist[wave][c] = __popcll(m);
      if (n == c) mymask = m;
    }
    __syncthreads();
    if (o < 32) {
      int c = o + 1, s = 0;
#pragma unroll
      for (int w = 0; w < 16; ++w) s += sm.u.s3.whist[w][c];
      sm.u.s3.clstot[c] = s;
    }
    __syncthreads();
    if (o == 0) {
      int run = 0;
#pragma unroll
      for (int c = 1; c <= 32; ++c) { sm.u.s3.clsofs[c] = run; run += sm.u.s3.clstot[c]; }
      sm.u.s3.clsofs[33] = run;
    }
    __syncthreads();
    if (o < 32) {
      int c = o + 1, s = sm.u.s3.clsofs[c];
#pragma unroll
      for (int w = 0; w < 16; ++w) { sm.u.s3.wofs[w][c] = s; s += sm.u.s3.whist[w][c]; }
    }
    __syncthreads();
    if (n) {
      int pos = sm.u.s3.wofs[wave][n] + __popcll(mymask & ((1ull << lane) - 1ull));
      sm.sidx[pos] = (unsigned short)o;
    }
    if (o < 33) sm.sseg[o] = sm.u.s3.clsofs[o + 1];
  }
  __syncthreads();

  // ---- S4: layer-1 class-sums + divisor LIF + compaction ----
  {
    float S[32];
#pragma unroll
    for (int c = 0; c < 32; ++c) {
      int j0 = __builtin_amdgcn_readfirstlane((c == 0) ? 0 : sm.sseg[c - 1]);
      int j1 = __builtin_amdgcn_readfirstlane(sm.sseg[c]);
      float s = 0.f;
      for (int j = j0; j < j1; ++j)
        s += W1T[(size_t)sm.sidx[j] * 1024 + o];
      S[c] = s;
    }
    const float bias = b1[o];
    float v = 0.f;
    unsigned word = 0u;
#pragma unroll
    for (int t = 0; t < 32; ++t) {
      float cur = 0.f;
#pragma unroll
      for (int c = 1; c <= 32; ++c)
        if ((t + 1) % c == 0) cur += S[c - 1];   // compile-time divisor table
      float xc = cur + bias;
      v = v + (xc - v) * 0.5f;
      if (v >= 1.0f) { word |= 1u << t; v = 0.f; }
    }
    bool act = (word != 0u);
    unsigned long long m = __ballot(act);
    if (lane == 0) sm.u.s4.wtot[wave] = __popcll(m);
    __syncthreads();
    if (o == 0) {
      int s = 0;
#pragma unroll
      for (int i = 0; i < 16; ++i) { sm.u.s4.wbase[i] = s; s += sm.u.s4.wtot[i]; }
      sm.mtot = s;
    }
    __syncthreads();
    if (act) {
      int pos = sm.u.s4.wbase[wave] + __popcll(m & ((1ull << lane) - 1ull));
      sm.l2i[pos] = (unsigned)o;
      sm.l2w[pos] = word;
    }
  }
  __syncthreads();

  // ---- S5: layer-2 sparse FC + LIF + count ----
  {
    for (int i = o; i < 10240; i += 1024)
      sm.u.s5.sW2[(i >> 10) * 1025 + (i & 1023)] = W2[i];
    __syncthreads();
    const int mtot = sm.mtot;
    if (o < 320) {
      int t = o / 10, c = o - t * 10;
      float acc = 0.f;
      for (int j = 0; j < mtot; ++j) {
        unsigned wd = sm.l2w[j];
        float wv = sm.u.s5.sW2[c * 1025 + sm.l2i[j]];
        acc += ((wd >> t) & 1u) ? wv : 0.f;
      }
      sm.u.s5.scur[o] = acc;
    }
    __syncthreads();
    if (o < 10) {
      float v = 0.f, cnt2 = 0.f, bias = b2[o];
#pragma unroll
      for (int tt = 0; tt < 32; ++tt) {
        float xc = sm.u.s5.scur[tt * 10 + o] + bias;
        v = v + (xc - v) * 0.5f;
        if (v >= 1.0f) { cnt2 += 1.f; v = 0.f; }
      }
      out[(size_t)b * 10 + o] = cnt2;
    }
  }
}

// ---------------------------------------------------------------------------
extern "C" void kernel_launch(void* const* d_in, const int* in_sizes, int n_in,
                              void* d_out, int out_size, void* d_ws, size_t ws_size,
                              hipStream_t stream) {
  const float* x  = (const float*)d_in[0];   // [512,784]
  const float* W0 = (const float*)d_in[1];   // [1024,784]
  const float* b0 = (const float*)d_in[2];   // [1024]
  const float* W1 = (const float*)d_in[3];   // [1024,1024]
  const float* b1 = (const float*)d_in[4];   // [1024]
  const float* W2 = (const float*)d_in[5];   // [10,1024]
  const float* b2 = (const float*)d_in[6];   // [10]
  float* out = (float*)d_out;                // [512,10]

  char* ws = (char*)d_ws;
  size_t off = 0;
  auto alloc = [&](size_t bytes) -> char* {
    char* p = ws + off;
    off += (bytes + 255) & ~(size_t)255;
    return p;
  };
  __hip_bfloat16* Ax    = (__hip_bfloat16*)alloc((size_t)512 * 4800 * 2);   // 4.7 MB
  __hip_bfloat16* Bw    = (__hip_bfloat16*)alloc((size_t)1024 * 4800 * 2);  // 9.4 MB
  float*          Cpart = (float*)alloc((size_t)10 * 512 * 1024 * 4);       // 21 MB
  float*          W1T   = (float*)alloc((size_t)1024 * 1024 * 4);           // 4.2 MB
  (void)ws_size;

  prep_k<<<4800, 256, 0, stream>>>(x, W0, Ax, Bw);
  gemm0t_k<<<1344, 256, 0, stream>>>(Ax, Bw, W1, W1T, Cpart);
  tail_k<<<512, 1024, 0, stream>>>(Cpart, b0, W1T, b1, W2, b2, out);
}